// Round 7
// baseline (359.284 us; speedup 1.0000x reference)
//
#include <hip/hip_runtime.h>
#include <math.h>

#define ROWLEN 4096
#define BLK 256
#define NBLOCKS 2048   // 8 blocks/CU x 256 CU; each block handles rows/NBLOCKS rows

__device__ __forceinline__ float max3f(float a, float b, float c) {
    return fmaxf(fmaxf(a, b), c);   // fuses to v_max3_f32
}

struct Quad { float q0, q1, q2, q3; };   // sorted descending

// branchless full sort of 4 values, descending (5-comparator network)
__device__ __forceinline__ Quad sort4(float4 v) {
    float p0 = fmaxf(v.x, v.y), p1 = fminf(v.x, v.y);
    float p2 = fmaxf(v.z, v.w), p3 = fminf(v.z, v.w);
    float q0 = fmaxf(p0, p2),  t2 = fminf(p0, p2);
    float t1 = fmaxf(p1, p3),  q3 = fminf(p1, p3);
    Quad r;
    r.q0 = q0;
    r.q1 = fmaxf(t1, t2);
    r.q2 = fminf(t1, t2);
    r.q3 = q3;
    return r;
}

// branchless top-4 of the union of two sorted quads
__device__ __forceinline__ void merge4(Quad& a, const Quad& b) {
    float m0 = fminf(a.q0, b.q0);
    float M1 = fmaxf(a.q1, b.q1);
    float r0 = fmaxf(a.q0, b.q0);
    float r1 = fmaxf(M1, m0);
    float r2 = max3f(fminf(M1, m0), a.q2, b.q2);
    float c1 = fminf(a.q2, b.q0);
    float c2 = fminf(a.q0, b.q2);
    float m1 = fminf(a.q1, b.q1);
    float M3 = fmaxf(a.q3, b.q3);
    float r3 = max3f(fmaxf(c1, c2), m1, M3);
    a.q0 = r0; a.q1 = r1; a.q2 = r2; a.q3 = r3;
}

// exact ordering for the rare-tie fallback (matches jax.lax.top_k)
__device__ __forceinline__ bool better(float v, int i, float w, int j) {
    return (v > w) || (v == w && i < j);
}

__global__ __launch_bounds__(BLK, 8) void topk_softmax_kernel(const float* __restrict__ in,
                                                              float* __restrict__ out,
                                                              int rows) {
    const int tid  = threadIdx.x;
    const int wave = tid >> 6;

    __shared__ float4 sq[2][4];   // double-buffered wave quads (parity per row)
    __shared__ float  f_p[3];
    __shared__ int    f_idx[3];

    int row = blockIdx.x;
    const int stride = gridDim.x;

    // prologue: load first row (coalesced float4, 16 elems/thread)
    const float4* rin = reinterpret_cast<const float4*>(in + (size_t)row * ROWLEN);
    float4 d0 = rin[tid];
    float4 d1 = rin[tid + BLK];
    float4 d2 = rin[tid + 2 * BLK];
    float4 d3 = rin[tid + 3 * BLK];

    int par = 0;
    for (;;) {
        // ---- reduce current row: per-thread top-4, then 64-lane butterfly ----
        Quad a = sort4(d0);
        Quad b = sort4(d1);
        Quad c = sort4(d2);
        Quad e = sort4(d3);
        merge4(a, b);
        merge4(c, e);
        merge4(a, c);
        #pragma unroll
        for (int off = 1; off < 64; off <<= 1) {
            Quad s;
            s.q0 = __shfl_xor(a.q0, off);
            s.q1 = __shfl_xor(a.q1, off);
            s.q2 = __shfl_xor(a.q2, off);
            s.q3 = __shfl_xor(a.q3, off);
            merge4(a, s);
        }
        if ((tid & 63) == 0) sq[par][wave] = make_float4(a.q0, a.q1, a.q2, a.q3);

        // ---- prefetch next row (HBM latency hides under barrier+merge+select) ----
        const int  nrow      = row + stride;
        const bool have_next = (nrow < rows);
        float4 n0, n1, n2, n3;
        if (have_next) {
            const float4* rn = reinterpret_cast<const float4*>(in + (size_t)nrow * ROWLEN);
            n0 = rn[tid];
            n1 = rn[tid + BLK];
            n2 = rn[tid + 2 * BLK];
            n3 = rn[tid + 3 * BLK];
        }

        __syncthreads();
        float4 w0 = sq[par][0];
        Quad g; g.q0 = w0.x; g.q1 = w0.y; g.q2 = w0.z; g.q3 = w0.w;
        #pragma unroll
        for (int w = 1; w < 4; ++w) {
            float4 ww = sq[par][w];
            Quad h; h.q0 = ww.x; h.q1 = ww.y; h.q2 = ww.z; h.q3 = ww.w;
            merge4(g, h);
        }

        float4* rout = reinterpret_cast<float4*>(out + (size_t)row * ROWLEN);

        // tie at rank-3 boundary  <=>  4th value equals 3rd (block-uniform)
        if (g.q3 != g.q2) {
            const float a0 = g.q0, a1 = g.q1, a2 = g.q2;
            const float e1   = __expf(a1 - a0);
            const float e2   = __expf(a2 - a0);
            const float invZ = 1.0f / (1.0f + e1 + e2);
            const float p0 = invZ, p1 = e1 * invZ, p2 = e2 * invZ;

            #pragma unroll
            for (int k = 0; k < 4; ++k) {
                const float4 v = (k == 0) ? d0 : (k == 1) ? d1 : (k == 2) ? d2 : d3;
                float4 o;
                o.x = (v.x < a2) ? 0.0f : (v.x < a1) ? p2 : (v.x < a0) ? p1 : p0;
                o.y = (v.y < a2) ? 0.0f : (v.y < a1) ? p2 : (v.y < a0) ? p1 : p0;
                o.z = (v.z < a2) ? 0.0f : (v.z < a1) ? p2 : (v.z < a0) ? p1 : p0;
                o.w = (v.w < a2) ? 0.0f : (v.w < a1) ? p2 : (v.w < a0) ? p1 : p0;
                rout[tid + k * BLK] = o;
            }
        } else {
            // rare exact fallback (block-uniform): thread 0 re-scans with index tie-break
            if (tid == 0) {
                const float* r = in + (size_t)row * ROWLEN;
                float v0 = -INFINITY, v1 = -INFINITY, v2 = -INFINITY;
                int   i0 = 0x7fffffff, i1 = 0x7fffffff, i2 = 0x7fffffff;
                for (int j = 0; j < ROWLEN; ++j) {
                    float v = r[j];
                    if (better(v, j, v2, i2)) {
                        if (better(v, j, v1, i1)) {
                            v2 = v1; i2 = i1;
                            if (better(v, j, v0, i0)) { v1 = v0; i1 = i0; v0 = v; i0 = j; }
                            else                      { v1 = v;  i1 = j; }
                        } else { v2 = v; i2 = j; }
                    }
                }
                const float e1 = __expf(v1 - v0), e2 = __expf(v2 - v0);
                const float invZ = 1.0f / (1.0f + e1 + e2);
                f_p[0] = invZ; f_p[1] = e1 * invZ; f_p[2] = e2 * invZ;
                f_idx[0] = i0; f_idx[1] = i1; f_idx[2] = i2;
            }
            __syncthreads();
            const float p0 = f_p[0], p1 = f_p[1], p2 = f_p[2];
            const int   t0 = f_idx[0], t1 = f_idx[1], t2 = f_idx[2];
            #pragma unroll
            for (int k = 0; k < 4; ++k) {
                const int e2i = 4 * (tid + k * BLK);
                float4 o;
                o.x = (e2i + 0 == t0) ? p0 : (e2i + 0 == t1) ? p1 : (e2i + 0 == t2) ? p2 : 0.0f;
                o.y = (e2i + 1 == t0) ? p0 : (e2i + 1 == t1) ? p1 : (e2i + 1 == t2) ? p2 : 0.0f;
                o.z = (e2i + 2 == t0) ? p0 : (e2i + 2 == t1) ? p1 : (e2i + 2 == t2) ? p2 : 0.0f;
                o.w = (e2i + 3 == t0) ? p0 : (e2i + 3 == t1) ? p1 : (e2i + 3 == t2) ? p2 : 0.0f;
                rout[tid + k * BLK] = o;
            }
        }

        if (!have_next) break;
        d0 = n0; d1 = n1; d2 = n2; d3 = n3;
        row = nrow;
        par ^= 1;
    }
}

extern "C" void kernel_launch(void* const* d_in, const int* in_sizes, int n_in,
                              void* d_out, int out_size, void* d_ws, size_t ws_size,
                              hipStream_t stream) {
    const float* in  = (const float*)d_in[0];
    float*       out = (float*)d_out;
    const int rows   = in_sizes[0] / ROWLEN;    // 8*2048 = 16384
    int blocks = NBLOCKS;
    if (blocks > rows) blocks = rows;
    topk_softmax_kernel<<<blocks, BLK, 0, stream>>>(in, out, rows);
}

// Round 8
// 99.595 us; speedup vs baseline: 3.6075x; 3.6075x over previous
//
#include <hip/hip_runtime.h>
#include <math.h>

#define ROWLEN 4096
#define BLK 256

typedef float vfloat4 __attribute__((ext_vector_type(4)));
typedef unsigned long long u64;

// ---------- pass 1: pure streaming. top-3 u64 keys per lane + zero-fill ----------
// key = (monotone(value) << 32) | (4095 - idx)  ->  u64 '>' == jax.lax.top_k order
// (higher value wins; equal value -> lower index wins). Keys are unique -> exact.

__device__ __forceinline__ void fold_key(float v, int idx,
                                         u64& t0, u64& t1, u64& t2) {
    unsigned u = __float_as_uint(v);
    unsigned s = ((unsigned)(((int)u) >> 31)) | 0x80000000u;  // neg: ~u, pos: u^0x80000000
    u64 k = ((u64)(u ^ s) << 32) | (unsigned)(4095 - idx);
    bool c0 = k > t0, c1 = k > t1, c2 = k > t2;
    t2 = c2 ? (c1 ? t1 : k) : t2;   // reads old t1
    t1 = c1 ? (c0 ? t0 : k) : t1;   // reads old t0
    t0 = c0 ? k : t0;
}

__global__ __launch_bounds__(BLK, 4) void pass1_stream(const float* __restrict__ in,
                                                       float* __restrict__ out,
                                                       u64* __restrict__ ws,
                                                       int rows) {
    const int lane = threadIdx.x & 63;
    const int row  = blockIdx.x * 4 + (threadIdx.x >> 6);
    if (row >= rows) return;

    const float4* rin  = reinterpret_cast<const float4*>(in  + (size_t)row * ROWLEN);
    vfloat4*      rout = reinterpret_cast<vfloat4*>(     out + (size_t)row * ROWLEN);

    // zero-fill this row: 16 independent fire-and-forget stores (nontemporal)
    vfloat4 z; z.x = 0.0f; z.y = 0.0f; z.z = 0.0f; z.w = 0.0f;
    #pragma unroll
    for (int j = 0; j < 16; ++j)
        __builtin_nontemporal_store(z, &rout[lane + 64 * j]);

    // streaming fold: 16 independent coalesced loads, dependent-only on tiny triple
    u64 t0 = 0, t1 = 0, t2 = 0;   // 0 == -inf sentinel (real keys always > 0)
    #pragma unroll
    for (int j = 0; j < 16; ++j) {
        float4 d = rin[lane + 64 * j];
        const int e = 4 * (lane + 64 * j);
        fold_key(d.x, e + 0, t0, t1, t2);
        fold_key(d.y, e + 1, t0, t1, t2);
        fold_key(d.z, e + 2, t0, t1, t2);
        fold_key(d.w, e + 3, t0, t1, t2);
    }

    // layout ws[row][rank][lane] -> coalesced 512B stores per rank
    u64* wrow = ws + (size_t)row * 192;
    wrow[lane]       = t0;
    wrow[64 + lane]  = t1;
    wrow[128 + lane] = t2;
}

// ---------- pass 2: tiny per-row reduce of 192 keys + scatter 3 probs ----------

__device__ __forceinline__ u64 umax64(u64 a, u64 b) { return a > b ? a : b; }
__device__ __forceinline__ u64 umin64(u64 a, u64 b) { return a < b ? a : b; }

// top-3 of the union of two sorted-descending u64 triples
__device__ __forceinline__ void merge3k(u64& a0, u64& a1, u64& a2,
                                        u64 b0, u64 b1, u64 b2) {
    u64 r0 = umax64(a0, b0);
    u64 m0 = umin64(a0, b0);
    u64 M1 = umax64(a1, b1);
    u64 r1 = umax64(m0, umin64(r0, M1));
    u64 r2 = umax64(umin64(M1, m0), umax64(a2, b2));
    a0 = r0; a1 = r1; a2 = r2;
}

__global__ __launch_bounds__(BLK, 4) void pass2_reduce(const u64* __restrict__ ws,
                                                       float* __restrict__ out,
                                                       int rows) {
    const int lane = threadIdx.x & 63;
    const int row  = blockIdx.x * 4 + (threadIdx.x >> 6);
    if (row >= rows) return;

    const u64* wrow = ws + (size_t)row * 192;
    u64 a0 = wrow[lane];          // each lane already holds a sorted triple
    u64 a1 = wrow[64 + lane];
    u64 a2 = wrow[128 + lane];

    #pragma unroll
    for (int off = 1; off < 64; off <<= 1) {
        u64 b0 = __shfl_xor(a0, off);
        u64 b1 = __shfl_xor(a1, off);
        u64 b2 = __shfl_xor(a2, off);
        merge3k(a0, a1, a2, b0, b1, b2);
    }

    if (lane == 0) {
        // decode keys -> (value, index)
        unsigned m0 = (unsigned)(a0 >> 32);
        unsigned m1 = (unsigned)(a1 >> 32);
        unsigned m2 = (unsigned)(a2 >> 32);
        unsigned u0 = ((int)m0 < 0) ? (m0 ^ 0x80000000u) : ~m0;
        unsigned u1 = ((int)m1 < 0) ? (m1 ^ 0x80000000u) : ~m1;
        unsigned u2 = ((int)m2 < 0) ? (m2 ^ 0x80000000u) : ~m2;
        float v0 = __uint_as_float(u0);
        float v1 = __uint_as_float(u1);
        float v2 = __uint_as_float(u2);
        int i0 = 4095 - (int)(unsigned)(a0 & 0xFFFFFFFFu);
        int i1 = 4095 - (int)(unsigned)(a1 & 0xFFFFFFFFu);
        int i2 = 4095 - (int)(unsigned)(a2 & 0xFFFFFFFFu);

        const float e1   = __expf(v1 - v0);
        const float e2   = __expf(v2 - v0);
        const float invZ = 1.0f / (1.0f + e1 + e2);

        float* r = out + (size_t)row * ROWLEN;
        r[i0] = invZ;
        r[i1] = e1 * invZ;
        r[i2] = e2 * invZ;
    }
}

// ---------- fallback (round-6 single kernel), used only if ws is too small ----------

__device__ __forceinline__ float max3f(float a, float b, float c) {
    return fmaxf(fmaxf(a, b), c);
}
struct Quad { float q0, q1, q2, q3; };
__device__ __forceinline__ Quad sort4(float4 v) {
    float p0 = fmaxf(v.x, v.y), p1 = fminf(v.x, v.y);
    float p2 = fmaxf(v.z, v.w), p3 = fminf(v.z, v.w);
    float q0 = fmaxf(p0, p2),  t2 = fminf(p0, p2);
    float t1 = fmaxf(p1, p3),  q3 = fminf(p1, p3);
    Quad r; r.q0 = q0; r.q1 = fmaxf(t1, t2); r.q2 = fminf(t1, t2); r.q3 = q3;
    return r;
}
__device__ __forceinline__ void merge4(Quad& a, const Quad& b) {
    float m0 = fminf(a.q0, b.q0);
    float M1 = fmaxf(a.q1, b.q1);
    float r0 = fmaxf(a.q0, b.q0);
    float r1 = fmaxf(M1, m0);
    float r2 = max3f(fminf(M1, m0), a.q2, b.q2);
    float c1 = fminf(a.q2, b.q0);
    float c2 = fminf(a.q0, b.q2);
    float m1 = fminf(a.q1, b.q1);
    float M3 = fmaxf(a.q3, b.q3);
    float r3 = max3f(fmaxf(c1, c2), m1, M3);
    a.q0 = r0; a.q1 = r1; a.q2 = r2; a.q3 = r3;
}
__device__ __forceinline__ bool better(float v, int i, float w, int j) {
    return (v > w) || (v == w && i < j);
}
__global__ __launch_bounds__(BLK, 8) void topk_softmax_fallback(const float* __restrict__ in,
                                                                float* __restrict__ out) {
    const int row = blockIdx.x;
    const float4* rin  = reinterpret_cast<const float4*>(in  + (size_t)row * ROWLEN);
    float4*       rout = reinterpret_cast<float4*>(      out + (size_t)row * ROWLEN);
    const int tid = threadIdx.x;
    float4 d0 = rin[tid];
    float4 d1 = rin[tid + BLK];
    float4 d2 = rin[tid + 2 * BLK];
    float4 d3 = rin[tid + 3 * BLK];
    Quad a = sort4(d0), b = sort4(d1), c = sort4(d2), e = sort4(d3);
    merge4(a, b); merge4(c, e); merge4(a, c);
    #pragma unroll
    for (int off = 1; off < 64; off <<= 1) {
        Quad s;
        s.q0 = __shfl_xor(a.q0, off);
        s.q1 = __shfl_xor(a.q1, off);
        s.q2 = __shfl_xor(a.q2, off);
        s.q3 = __shfl_xor(a.q3, off);
        merge4(a, s);
    }
    __shared__ float4 sq[4];
    __shared__ float  f_p[3];
    __shared__ int    f_idx[3];
    const int wave = tid >> 6;
    if ((tid & 63) == 0) sq[wave] = make_float4(a.q0, a.q1, a.q2, a.q3);
    __syncthreads();
    float4 w0 = sq[0];
    Quad g; g.q0 = w0.x; g.q1 = w0.y; g.q2 = w0.z; g.q3 = w0.w;
    #pragma unroll
    for (int w = 1; w < 4; ++w) {
        float4 ww = sq[w];
        Quad h; h.q0 = ww.x; h.q1 = ww.y; h.q2 = ww.z; h.q3 = ww.w;
        merge4(g, h);
    }
    if (g.q3 != g.q2) {
        const float a0 = g.q0, a1 = g.q1, a2 = g.q2;
        const float e1 = __expf(a1 - a0), e2 = __expf(a2 - a0);
        const float invZ = 1.0f / (1.0f + e1 + e2);
        const float p0 = invZ, p1 = e1 * invZ, p2 = e2 * invZ;
        #pragma unroll
        for (int k = 0; k < 4; ++k) {
            const float4 v = (k == 0) ? d0 : (k == 1) ? d1 : (k == 2) ? d2 : d3;
            float4 o;
            o.x = (v.x < a2) ? 0.0f : (v.x < a1) ? p2 : (v.x < a0) ? p1 : p0;
            o.y = (v.y < a2) ? 0.0f : (v.y < a1) ? p2 : (v.y < a0) ? p1 : p0;
            o.z = (v.z < a2) ? 0.0f : (v.z < a1) ? p2 : (v.z < a0) ? p1 : p0;
            o.w = (v.w < a2) ? 0.0f : (v.w < a1) ? p2 : (v.w < a0) ? p1 : p0;
            rout[tid + k * BLK] = o;
        }
    } else {
        if (tid == 0) {
            const float* r = in + (size_t)row * ROWLEN;
            float v0 = -INFINITY, v1 = -INFINITY, v2 = -INFINITY;
            int   i0 = 0x7fffffff, i1 = 0x7fffffff, i2 = 0x7fffffff;
            for (int j = 0; j < ROWLEN; ++j) {
                float v = r[j];
                if (better(v, j, v2, i2)) {
                    if (better(v, j, v1, i1)) {
                        v2 = v1; i2 = i1;
                        if (better(v, j, v0, i0)) { v1 = v0; i1 = i0; v0 = v; i0 = j; }
                        else                      { v1 = v;  i1 = j; }
                    } else { v2 = v; i2 = j; }
                }
            }
            const float e1 = __expf(v1 - v0), e2 = __expf(v2 - v0);
            const float invZ = 1.0f / (1.0f + e1 + e2);
            f_p[0] = invZ; f_p[1] = e1 * invZ; f_p[2] = e2 * invZ;
            f_idx[0] = i0; f_idx[1] = i1; f_idx[2] = i2;
        }
        __syncthreads();
        const float p0 = f_p[0], p1 = f_p[1], p2 = f_p[2];
        const int   t0 = f_idx[0], t1 = f_idx[1], t2 = f_idx[2];
        #pragma unroll
        for (int k = 0; k < 4; ++k) {
            const int e2i = 4 * (tid + k * BLK);
            float4 o;
            o.x = (e2i + 0 == t0) ? p0 : (e2i + 0 == t1) ? p1 : (e2i + 0 == t2) ? p2 : 0.0f;
            o.y = (e2i + 1 == t0) ? p0 : (e2i + 1 == t1) ? p1 : (e2i + 1 == t2) ? p2 : 0.0f;
            o.z = (e2i + 2 == t0) ? p0 : (e2i + 2 == t1) ? p1 : (e2i + 2 == t2) ? p2 : 0.0f;
            o.w = (e2i + 3 == t0) ? p0 : (e2i + 3 == t1) ? p1 : (e2i + 3 == t2) ? p2 : 0.0f;
            rout[tid + k * BLK] = o;
        }
    }
}

extern "C" void kernel_launch(void* const* d_in, const int* in_sizes, int n_in,
                              void* d_out, int out_size, void* d_ws, size_t ws_size,
                              hipStream_t stream) {
    const float* in  = (const float*)d_in[0];
    float*       out = (float*)d_out;
    const int rows   = in_sizes[0] / ROWLEN;            // 8*2048 = 16384
    const size_t need = (size_t)rows * 192 * sizeof(u64);   // 25.2 MB

    if (ws_size >= need) {
        const int blocks = (rows + 3) / 4;              // 4 rows (waves) per block
        pass1_stream<<<blocks, BLK, 0, stream>>>(in, out, (u64*)d_ws, rows);
        pass2_reduce<<<blocks, BLK, 0, stream>>>((const u64*)d_ws, out, rows);
    } else {
        topk_softmax_fallback<<<rows, BLK, 0, stream>>>(in, out);
    }
}

// Round 9
// 94.510 us; speedup vs baseline: 3.8015x; 1.0538x over previous
//
#include <hip/hip_runtime.h>
#include <math.h>

#define ROWLEN 4096
#define BLK 256

typedef float vfloat4 __attribute__((ext_vector_type(4)));
typedef unsigned long long u64;

// key = (monotone(value) << 32) | (4095 - idx): u64 '>' == jax.lax.top_k order
// (higher value wins; equal value -> lower index wins). Keys unique -> exact, no ties.
__device__ __forceinline__ void fold_key(float v, int idx,
                                         u64& t0, u64& t1, u64& t2) {
    unsigned u = __float_as_uint(v);
    unsigned s = ((unsigned)(((int)u) >> 31)) | 0x80000000u;  // neg: ~u, pos: u^0x80000000
    u64 k = ((u64)(u ^ s) << 32) | (unsigned)(4095 - idx);
    bool c0 = k > t0, c1 = k > t1, c2 = k > t2;
    t2 = c2 ? (c1 ? t1 : k) : t2;   // reads old t1
    t1 = c1 ? (c0 ? t0 : k) : t1;   // reads old t0
    t0 = c0 ? k : t0;
}

__device__ __forceinline__ u64 umax64(u64 a, u64 b) { return a > b ? a : b; }
__device__ __forceinline__ u64 umin64(u64 a, u64 b) { return a < b ? a : b; }

// top-3 of the union of two sorted-descending u64 triples (validated round 8)
__device__ __forceinline__ void merge3k(u64& a0, u64& a1, u64& a2,
                                        u64 b0, u64 b1, u64 b2) {
    u64 r0 = umax64(a0, b0);
    u64 m0 = umin64(a0, b0);
    u64 M1 = umax64(a1, b1);
    u64 r1 = umax64(m0, umin64(r0, M1));
    u64 r2 = umax64(umin64(M1, m0), umax64(a2, b2));
    a0 = r0; a1 = r1; a2 = r2;
}

__global__ __launch_bounds__(BLK, 4) void topk_softmax_fused(const float* __restrict__ in,
                                                             float* __restrict__ out,
                                                             int rows) {
    const int lane = threadIdx.x & 63;
    const int row  = blockIdx.x * 4 + (threadIdx.x >> 6);
    if (row >= rows) return;

    const float4* rin  = reinterpret_cast<const float4*>(in  + (size_t)row * ROWLEN);
    vfloat4*      rout = reinterpret_cast<vfloat4*>(     out + (size_t)row * ROWLEN);

    // zero-fill this row first: 16 independent nontemporal stores, overlap the loads
    vfloat4 z; z.x = 0.0f; z.y = 0.0f; z.z = 0.0f; z.w = 0.0f;
    #pragma unroll
    for (int j = 0; j < 16; ++j)
        __builtin_nontemporal_store(z, &rout[lane + 64 * j]);

    // streaming fold: 16 independent coalesced loads -> per-lane sorted key triple
    u64 t0 = 0, t1 = 0, t2 = 0;   // 0 == -inf sentinel (real keys always > 0)
    #pragma unroll
    for (int j = 0; j < 16; ++j) {
        float4 d = rin[lane + 64 * j];
        const int e = 4 * (lane + 64 * j);
        fold_key(d.x, e + 0, t0, t1, t2);
        fold_key(d.y, e + 1, t0, t1, t2);
        fold_key(d.z, e + 2, t0, t1, t2);
        fold_key(d.w, e + 3, t0, t1, t2);
    }

    // 64-lane butterfly: all lanes converge to the row's top-3 keys
    #pragma unroll
    for (int off = 1; off < 64; off <<= 1) {
        u64 b0 = __shfl_xor(t0, off);
        u64 b1 = __shfl_xor(t1, off);
        u64 b2 = __shfl_xor(t2, off);
        merge3k(t0, t1, t2, b0, b1, b2);
    }

    // drain the wave's zero-fill stores before scattering into the same row
    // (stores from DIFFERENT lanes to the winner addresses must land first)
    asm volatile("s_waitcnt vmcnt(0)" ::: "memory");

    if (lane == 0) {
        unsigned m0 = (unsigned)(t0 >> 32);
        unsigned m1 = (unsigned)(t1 >> 32);
        unsigned m2 = (unsigned)(t2 >> 32);
        unsigned u0 = ((int)m0 < 0) ? (m0 ^ 0x80000000u) : ~m0;
        unsigned u1 = ((int)m1 < 0) ? (m1 ^ 0x80000000u) : ~m1;
        unsigned u2 = ((int)m2 < 0) ? (m2 ^ 0x80000000u) : ~m2;
        float v0 = __uint_as_float(u0);
        float v1 = __uint_as_float(u1);
        float v2 = __uint_as_float(u2);
        int i0 = 4095 - (int)(unsigned)(t0 & 0xFFFFFFFFu);
        int i1 = 4095 - (int)(unsigned)(t1 & 0xFFFFFFFFu);
        int i2 = 4095 - (int)(unsigned)(t2 & 0xFFFFFFFFu);

        const float e1   = __expf(v1 - v0);
        const float e2   = __expf(v2 - v0);
        const float invZ = 1.0f / (1.0f + e1 + e2);

        float* r = out + (size_t)row * ROWLEN;
        r[i0] = invZ;
        r[i1] = e1 * invZ;
        r[i2] = e2 * invZ;
    }
}

extern "C" void kernel_launch(void* const* d_in, const int* in_sizes, int n_in,
                              void* d_out, int out_size, void* d_ws, size_t ws_size,
                              hipStream_t stream) {
    const float* in  = (const float*)d_in[0];
    float*       out = (float*)d_out;
    const int rows   = in_sizes[0] / ROWLEN;     // 8*2048 = 16384
    const int blocks = (rows + 3) / 4;           // 4 rows (waves) per block
    topk_softmax_fused<<<blocks, BLK, 0, stream>>>(in, out, rows);
}